// Round 1
// baseline (72.698 us; speedup 1.0000x reference)
//
#include <hip/hip_runtime.h>

#define Hh 64
#define Ww 64
#define Cc 128
#define ND 64
#define BSz 32
#define TOPK 4096

typedef short s16x4 __attribute__((ext_vector_type(4)));
typedef short bf16x8 __attribute__((ext_vector_type(8)));
typedef unsigned short u16x8 __attribute__((ext_vector_type(8)));
typedef float f32x4 __attribute__((ext_vector_type(4)));

static __device__ __forceinline__ unsigned short f2bf(float f) {
    unsigned int u = __builtin_bit_cast(unsigned int, f);
    u += 0x7fffu + ((u >> 16) & 1u);   // RNE (finite data; no NaN path needed)
    return (unsigned short)(u >> 16);
}
static __device__ __forceinline__ float bf2f(unsigned short s) {
    unsigned int u = ((unsigned int)s) << 16;
    return __builtin_bit_cast(float, u);
}

// ---------------- Kernel 1: NCHW fp32 -> NHWC bf16 ----------------
__global__ __launch_bounds__(256) void k_transpose(const float* __restrict__ fm,
                                                   unsigned short* __restrict__ fmT) {
    const int blk = blockIdx.x;          // b*64 + y
    const int b = blk >> 6, y = blk & 63;
    const int t = threadIdx.x;
    const int x  = t >> 2;               // 0..63
    const int c0 = (t & 3) * 32;         // 0,32,64,96

    const float* src = fm + (((size_t)b * Cc) * Hh + y) * Ww + x;
    unsigned short buf[32];
#pragma unroll
    for (int j = 0; j < 32; ++j) {
        float v = src[(size_t)(c0 + j) * (Hh * Ww)];
        buf[j] = f2bf(v);
    }
    unsigned short* dst = fmT + (((size_t)b * Hh + y) * Ww + x) * Cc + c0;
#pragma unroll
    for (int j = 0; j < 4; ++j) {
        *(u16x8*)(dst + j * 8) = *(const u16x8*)(buf + j * 8);
    }
}

// ---------------- Kernel 2: fused gather + MLP + normalize ----------------
// block = 256 threads (4 waves), 128 samples per block.
__global__ __launch_bounds__(256) void k_fused(const unsigned short* __restrict__ fmT,
                                               const float* __restrict__ pc,
                                               const float* __restrict__ W1,
                                               const float* __restrict__ b1,
                                               const float* __restrict__ W2,
                                               const float* __restrict__ b2,
                                               float* __restrict__ out) {
    __shared__ unsigned short sampA[128][136];   // M x K(128), +8 pad  (34816 B)
    __shared__ unsigned short w1t[64][136];      // W1^T: [n][k=c]      (17408 B)
    __shared__ unsigned short w2t[64][72];       // W2^T: [n][k]        ( 9216 B)
    __shared__ float bias1[64];
    __shared__ float bias2[64];
    // h (128x64 bf16, stride 72) overlays sampA after GEMM1 (barrier-protected)
    unsigned short (*hbuf)[72] = reinterpret_cast<unsigned short (*)[72]>(&sampA[0][0]);

    const int t  = threadIdx.x;
    const int s0 = blockIdx.x * 128;

    // ---- phase 0: stage weights/biases ----
#pragma unroll
    for (int i = 0; i < 32; ++i) {
        int e = t + 256 * i;                 // 8192 = 128*64
        w1t[e & 63][e >> 6] = f2bf(W1[e]);   // w1t[d][c] = W1[c][d]
    }
#pragma unroll
    for (int i = 0; i < 16; ++i) {
        int e = t + 256 * i;                 // 4096 = 64*64
        w2t[e & 63][e >> 6] = f2bf(W2[e]);
    }
    if (t < 64) { bias1[t] = b1[t]; bias2[t] = b2[t]; }

    // ---- phase 1: bilinear gather into sampA (2 threads / sample) ----
    {
        const int s   = t >> 1;
        const int ch0 = (t & 1) * 64;
        const int gs  = s0 + s;
        const float y = pc[2 * (size_t)gs + 0];
        const float x = pc[2 * (size_t)gs + 1];
        const float yf = floorf(y), xf = floorf(x);
        const float ty = y - yf, tx = x - xf;
        int y0 = min(max((int)yf, 0), Hh - 1);
        int x0 = min(max((int)xf, 0), Ww - 1);
        int y1 = min(y0 + 1, Hh - 1);
        int x1 = min(x0 + 1, Ww - 1);
        const float w00 = (1.f - ty) * (1.f - tx), w01 = (1.f - ty) * tx;
        const float w10 = ty * (1.f - tx),         w11 = ty * tx;
        const int b = gs >> 12;   // / TOPK
        const unsigned short* base = fmT + (size_t)b * (Hh * Ww * Cc) + ch0;
        const u16x8* p00 = (const u16x8*)(base + (y0 * Ww + x0) * Cc);
        const u16x8* p01 = (const u16x8*)(base + (y0 * Ww + x1) * Cc);
        const u16x8* p10 = (const u16x8*)(base + (y1 * Ww + x0) * Cc);
        const u16x8* p11 = (const u16x8*)(base + (y1 * Ww + x1) * Cc);
#pragma unroll
        for (int j = 0; j < 8; ++j) {
            u16x8 a = p00[j], bb = p01[j], c = p10[j], d = p11[j];
            u16x8 o;
#pragma unroll
            for (int k = 0; k < 8; ++k) {
                float v = w00 * bf2f(a[k]) + w01 * bf2f(bb[k])
                        + w10 * bf2f(c[k]) + w11 * bf2f(d[k]);
                o[k] = f2bf(v);
            }
            *(u16x8*)&sampA[s][ch0 + 8 * j] = o;
        }
    }
    __syncthreads();

    // ---- phase 2: GEMM1 (sampled @ W1) via MFMA ----
    const int lane = t & 63;
    const int wv   = t >> 6;
    const int m0   = wv * 32;       // wave's 32-row M band
    const int g    = lane >> 4;
    const int mr   = lane & 15;

    f32x4 acc[2][4];
#pragma unroll
    for (int mt = 0; mt < 2; ++mt)
#pragma unroll
        for (int nt = 0; nt < 4; ++nt) acc[mt][nt] = (f32x4){0.f, 0.f, 0.f, 0.f};

#pragma unroll
    for (int kk = 0; kk < 4; ++kk) {
        const int kb = kk * 32 + 8 * g;   // same (lane,elem)->k map for A and B => exact
        bf16x8 aF0 = *(const bf16x8*)&sampA[m0 + mr][kb];
        bf16x8 aF1 = *(const bf16x8*)&sampA[m0 + 16 + mr][kb];
#pragma unroll
        for (int nt = 0; nt < 4; ++nt) {
            bf16x8 bF = *(const bf16x8*)&w1t[nt * 16 + mr][kb];
            acc[0][nt] = __builtin_amdgcn_mfma_f32_16x16x32_bf16(aF0, bF, acc[0][nt], 0, 0, 0);
            acc[1][nt] = __builtin_amdgcn_mfma_f32_16x16x32_bf16(aF1, bF, acc[1][nt], 0, 0, 0);
        }
    }
    __syncthreads();   // all sampA reads done chip-wide before h overlays it

    // ---- phase 3: bias + ReLU, stage h (bf16) into LDS overlay ----
#pragma unroll
    for (int mt = 0; mt < 2; ++mt)
#pragma unroll
        for (int nt = 0; nt < 4; ++nt) {
            const int col = nt * 16 + mr;
            const float bb = bias1[col];
#pragma unroll
            for (int r = 0; r < 4; ++r) {
                const int row = m0 + mt * 16 + 4 * g + r;
                hbuf[row][col] = f2bf(fmaxf(acc[mt][nt][r] + bb, 0.f));
            }
        }
    // wave-local: GEMM2 below reads only rows this wave just wrote (in-order LDS)

    // ---- phase 4: GEMM2 (h @ W2), C initialized with bias2 ----
    f32x4 acc2[2][4];
#pragma unroll
    for (int mt = 0; mt < 2; ++mt)
#pragma unroll
        for (int nt = 0; nt < 4; ++nt) {
            const float bc = bias2[nt * 16 + mr];
            acc2[mt][nt] = (f32x4){bc, bc, bc, bc};
        }
#pragma unroll
    for (int kk = 0; kk < 2; ++kk) {
        const int kb = kk * 32 + 8 * g;
        bf16x8 aF0 = *(const bf16x8*)&hbuf[m0 + mr][kb];
        bf16x8 aF1 = *(const bf16x8*)&hbuf[m0 + 16 + mr][kb];
#pragma unroll
        for (int nt = 0; nt < 4; ++nt) {
            bf16x8 bF = *(const bf16x8*)&w2t[nt * 16 + mr][kb];
            acc2[0][nt] = __builtin_amdgcn_mfma_f32_16x16x32_bf16(aF0, bF, acc2[0][nt], 0, 0, 0);
            acc2[1][nt] = __builtin_amdgcn_mfma_f32_16x16x32_bf16(aF1, bF, acc2[1][nt], 0, 0, 0);
        }
    }

    // ---- phase 5: row-normalize (reduce across 16 lanes, 4 N-tiles) + store ----
#pragma unroll
    for (int mt = 0; mt < 2; ++mt) {
        f32x4 ss = (f32x4){0.f, 0.f, 0.f, 0.f};
#pragma unroll
        for (int nt = 0; nt < 4; ++nt)
#pragma unroll
            for (int r = 0; r < 4; ++r) ss[r] += acc2[mt][nt][r] * acc2[mt][nt][r];
#pragma unroll
        for (int off = 1; off <= 8; off <<= 1) {
#pragma unroll
            for (int r = 0; r < 4; ++r) ss[r] += __shfl_xor(ss[r], off);
        }
#pragma unroll
        for (int r = 0; r < 4; ++r) {
            const float inv = 1.f / fmaxf(sqrtf(ss[r]), 1e-12f);
            const size_t ob = (size_t)(s0 + m0 + mt * 16 + 4 * g + r) * ND;
#pragma unroll
            for (int nt = 0; nt < 4; ++nt)
                out[ob + nt * 16 + mr] = acc2[mt][nt][r] * inv;
        }
    }
}

extern "C" void kernel_launch(void* const* d_in, const int* in_sizes, int n_in,
                              void* d_out, int out_size, void* d_ws, size_t ws_size,
                              hipStream_t stream) {
    const float* fm = (const float*)d_in[0];
    const float* pc = (const float*)d_in[1];
    const float* W1 = (const float*)d_in[2];
    const float* b1 = (const float*)d_in[3];
    const float* W2 = (const float*)d_in[4];
    const float* b2 = (const float*)d_in[5];
    float* out = (float*)d_out;
    unsigned short* fmT = (unsigned short*)d_ws;   // 32 MB bf16 NHWC

    k_transpose<<<BSz * Hh, 256, 0, stream>>>(fm, fmT);
    k_fused<<<(BSz * TOPK) / 128, 256, 0, stream>>>(fmT, pc, W1, b1, W2, b2, out);
}

// Round 3
// 48.758 us; speedup vs baseline: 1.4910x; 1.4910x over previous
//
#include <hip/hip_runtime.h>

#define Hh 64
#define Ww 64
#define Cc 128
#define ND 64
#define BSz 32
#define TOPK 4096

typedef short bf16x8 __attribute__((ext_vector_type(8)));
typedef unsigned short u16x8 __attribute__((ext_vector_type(8)));
typedef float f32x4 __attribute__((ext_vector_type(4)));

static __device__ __forceinline__ unsigned short f2bf(float f) {
    unsigned int u = __builtin_bit_cast(unsigned int, f);
    u += 0x7fffu + ((u >> 16) & 1u);   // RNE (finite data; no NaN path needed)
    return (unsigned short)(u >> 16);
}
static __device__ __forceinline__ float bf2f(unsigned short s) {
    unsigned int u = ((unsigned int)s) << 16;
    return __builtin_bit_cast(float, u);
}

// ---------------- Kernel 1: NCHW fp32 -> NHWC bf16 ----------------
__global__ __launch_bounds__(256) void k_transpose(const float* __restrict__ fm,
                                                   unsigned short* __restrict__ fmT) {
    const int blk = blockIdx.x;          // b*64 + y
    const int b = blk >> 6, y = blk & 63;
    const int t = threadIdx.x;
    const int x  = t >> 2;               // 0..63
    const int c0 = (t & 3) * 32;         // 0,32,64,96

    const float* src = fm + (((size_t)b * Cc) * Hh + y) * Ww + x;
    unsigned short buf[32];
#pragma unroll
    for (int j = 0; j < 32; ++j) {
        float v = src[(size_t)(c0 + j) * (Hh * Ww)];
        buf[j] = f2bf(v);
    }
    unsigned short* dst = fmT + (((size_t)b * Hh + y) * Ww + x) * Cc + c0;
#pragma unroll
    for (int j = 0; j < 4; ++j) {
        *(u16x8*)(dst + j * 8) = *(const u16x8*)(buf + j * 8);
    }
}

// ---------------- Kernel 2: fused gather + MLP + normalize ----------------
// block = 256 threads (4 waves), 128 samples per block, gather -> registers.
__global__ __launch_bounds__(256) void k_fused(const unsigned short* __restrict__ fmT,
                                               const float* __restrict__ pc,
                                               const float* __restrict__ W1,
                                               const float* __restrict__ b1,
                                               const float* __restrict__ W2,
                                               const float* __restrict__ b2,
                                               float* __restrict__ out) {
    __shared__ unsigned short w1t[64][136];   // W1^T: [n][k=c]  (17408 B)
    __shared__ unsigned short w2t[64][72];    // W2^T: [n][k]    ( 9216 B)
    __shared__ unsigned short hbuf[128][72];  // h tile          (18432 B)
    __shared__ float bias1[64];
    __shared__ float bias2[64];

    const int t = threadIdx.x;
    // XCD-aware bijective swizzle. Grid is 1024 blocks -> chunk = 1024/8 = 128.
    // (Round-2 bug: chunk 256 assumed nwg=2048 -> OOB by 2x. 128 is bijective.)
    const int swz = (blockIdx.x & 7) * 128 + (blockIdx.x >> 3);
    const int s0  = swz * 128;

    const int lane = t & 63;
    const int wv   = t >> 6;
    const int m0   = wv * 32;       // wave's 32-row M band
    const int g    = lane >> 4;     // k-group 0..3
    const int mr   = lane & 15;     // row-in-tile

    // ---- phase 0: stage weights/biases (coalesced fp32 reads, L2-hot) ----
#pragma unroll
    for (int i = 0; i < 32; ++i) {
        int e = t + 256 * i;                 // 8192 = 128*64
        w1t[e & 63][e >> 6] = f2bf(W1[e]);   // w1t[d][c] = W1[c][d]
    }
#pragma unroll
    for (int i = 0; i < 16; ++i) {
        int e = t + 256 * i;                 // 4096 = 64*64
        w2t[e & 63][e >> 6] = f2bf(W2[e]);
    }
    if (t < 64) { bias1[t] = b1[t]; bias2[t] = b2[t]; }

    // ---- phase 1: bilinear gather DIRECTLY into A fragments (registers) ----
    // Lane (g,mr) owns rows m0+mr / m0+16+mr, channels kk*32 + 8g + j.
    bf16x8 aF[2][4];
#pragma unroll
    for (int half = 0; half < 2; ++half) {
        const int gs = s0 + m0 + half * 16 + mr;   // global sample idx
        const float y = pc[2 * (size_t)gs + 0];
        const float x = pc[2 * (size_t)gs + 1];
        const float yf = floorf(y), xf = floorf(x);
        const float ty = y - yf, tx = x - xf;
        int y0 = min(max((int)yf, 0), Hh - 1);
        int x0 = min(max((int)xf, 0), Ww - 1);
        int y1 = min(y0 + 1, Hh - 1);
        int x1 = min(x0 + 1, Ww - 1);
        const float w00 = (1.f - ty) * (1.f - tx), w01 = (1.f - ty) * tx;
        const float w10 = ty * (1.f - tx),         w11 = ty * tx;
        const int b = gs >> 12;   // / TOPK
        const unsigned short* base = fmT + (size_t)b * (Hh * Ww * Cc) + 8 * g;
        const u16x8* p00 = (const u16x8*)(base + (y0 * Ww + x0) * Cc);
        const u16x8* p01 = (const u16x8*)(base + (y0 * Ww + x1) * Cc);
        const u16x8* p10 = (const u16x8*)(base + (y1 * Ww + x0) * Cc);
        const u16x8* p11 = (const u16x8*)(base + (y1 * Ww + x1) * Cc);
#pragma unroll
        for (int kk = 0; kk < 4; ++kk) {
            u16x8 a = p00[4 * kk], bb = p01[4 * kk], c = p10[4 * kk], d = p11[4 * kk];
            u16x8 o;
#pragma unroll
            for (int k = 0; k < 8; ++k) {
                float v = w00 * bf2f(a[k]) + w01 * bf2f(bb[k])
                        + w10 * bf2f(c[k]) + w11 * bf2f(d[k]);
                o[k] = f2bf(v);
            }
            aF[half][kk] = __builtin_bit_cast(bf16x8, o);
        }
    }
    __syncthreads();   // weights staged

    // ---- phase 2: GEMM1 (sampled @ W1) via MFMA ----
    f32x4 acc[2][4];
#pragma unroll
    for (int mt = 0; mt < 2; ++mt)
#pragma unroll
        for (int nt = 0; nt < 4; ++nt) acc[mt][nt] = (f32x4){0.f, 0.f, 0.f, 0.f};

#pragma unroll
    for (int kk = 0; kk < 4; ++kk) {
        const int kb = kk * 32 + 8 * g;   // same (lane,elem)->k map as A gather => exact
#pragma unroll
        for (int nt = 0; nt < 4; ++nt) {
            bf16x8 bF = *(const bf16x8*)&w1t[nt * 16 + mr][kb];
            acc[0][nt] = __builtin_amdgcn_mfma_f32_16x16x32_bf16(aF[0][kk], bF, acc[0][nt], 0, 0, 0);
            acc[1][nt] = __builtin_amdgcn_mfma_f32_16x16x32_bf16(aF[1][kk], bF, acc[1][nt], 0, 0, 0);
        }
    }

    // ---- phase 3: bias + ReLU, stage h (bf16) into LDS (wave-local rows) ----
#pragma unroll
    for (int mt = 0; mt < 2; ++mt)
#pragma unroll
        for (int nt = 0; nt < 4; ++nt) {
            const int col = nt * 16 + mr;
            const float bb = bias1[col];
#pragma unroll
            for (int r = 0; r < 4; ++r) {
                const int row = m0 + mt * 16 + 4 * g + r;
                hbuf[row][col] = f2bf(fmaxf(acc[mt][nt][r] + bb, 0.f));
            }
        }
    // GEMM2 below reads only rows this wave just wrote (in-order LDS, no barrier)

    // ---- phase 4: GEMM2 (h @ W2), C initialized with bias2 ----
    f32x4 acc2[2][4];
#pragma unroll
    for (int mt = 0; mt < 2; ++mt)
#pragma unroll
        for (int nt = 0; nt < 4; ++nt) {
            const float bc = bias2[nt * 16 + mr];
            acc2[mt][nt] = (f32x4){bc, bc, bc, bc};
        }
#pragma unroll
    for (int kk = 0; kk < 2; ++kk) {
        const int kb = kk * 32 + 8 * g;
        bf16x8 aF0 = *(const bf16x8*)&hbuf[m0 + mr][kb];
        bf16x8 aF1 = *(const bf16x8*)&hbuf[m0 + 16 + mr][kb];
#pragma unroll
        for (int nt = 0; nt < 4; ++nt) {
            bf16x8 bF = *(const bf16x8*)&w2t[nt * 16 + mr][kb];
            acc2[0][nt] = __builtin_amdgcn_mfma_f32_16x16x32_bf16(aF0, bF, acc2[0][nt], 0, 0, 0);
            acc2[1][nt] = __builtin_amdgcn_mfma_f32_16x16x32_bf16(aF1, bF, acc2[1][nt], 0, 0, 0);
        }
    }

    // ---- phase 5: row-normalize (reduce across 16 lanes, 4 N-tiles) + store ----
#pragma unroll
    for (int mt = 0; mt < 2; ++mt) {
        f32x4 ss = (f32x4){0.f, 0.f, 0.f, 0.f};
#pragma unroll
        for (int nt = 0; nt < 4; ++nt)
#pragma unroll
            for (int r = 0; r < 4; ++r) ss[r] += acc2[mt][nt][r] * acc2[mt][nt][r];
#pragma unroll
        for (int off = 1; off <= 8; off <<= 1) {
#pragma unroll
            for (int r = 0; r < 4; ++r) ss[r] += __shfl_xor(ss[r], off);
        }
#pragma unroll
        for (int r = 0; r < 4; ++r) {
            const float inv = 1.f / fmaxf(sqrtf(ss[r]), 1e-12f);
            const size_t ob = (size_t)(s0 + m0 + mt * 16 + 4 * g + r) * ND;
#pragma unroll
            for (int nt = 0; nt < 4; ++nt)
                out[ob + nt * 16 + mr] = acc2[mt][nt][r] * inv;
        }
    }
}

extern "C" void kernel_launch(void* const* d_in, const int* in_sizes, int n_in,
                              void* d_out, int out_size, void* d_ws, size_t ws_size,
                              hipStream_t stream) {
    const float* fm = (const float*)d_in[0];
    const float* pc = (const float*)d_in[1];
    const float* W1 = (const float*)d_in[2];
    const float* b1 = (const float*)d_in[3];
    const float* W2 = (const float*)d_in[4];
    const float* b2 = (const float*)d_in[5];
    float* out = (float*)d_out;
    unsigned short* fmT = (unsigned short*)d_ws;   // 32 MB bf16 NHWC

    k_transpose<<<BSz * Hh, 256, 0, stream>>>(fm, fmT);
    k_fused<<<(BSz * TOPK) / 128, 256, 0, stream>>>(fmT, pc, W1, b1, W2, b2, out);
}

// Round 4
// 39.424 us; speedup vs baseline: 1.8440x; 1.2367x over previous
//
#include <hip/hip_runtime.h>

#define Hh 64
#define Ww 64
#define Cc 128   // FEAT_DIM
#define ND 64    // NODE_DIM
#define BSz 32
#define TOPK 4096
#define HW (Hh * Ww)
#define NPX (BSz * HW)      // 131072 pixels == samples count

typedef short bf16x8 __attribute__((ext_vector_type(8)));
typedef unsigned short u16x8 __attribute__((ext_vector_type(8)));
typedef float f32x4 __attribute__((ext_vector_type(4)));

static __device__ __forceinline__ unsigned short f2bf(float f) {
    unsigned int u = __builtin_bit_cast(unsigned int, f);
    u += 0x7fffu + ((u >> 16) & 1u);   // RNE (finite data)
    return (unsigned short)(u >> 16);
}
static __device__ __forceinline__ float bf2f(unsigned short s) {
    unsigned int u = ((unsigned int)s) << 16;
    return __builtin_bit_cast(float, u);
}

// ---------- k_prep: pack W1, W2 into MFMA B-fragment order (bf16) ----------
// w1p[i], i = ((nt*4+kk)*64 + l)*8 + j  -> W1[kk*32 + 8*(l>>4) + j][nt*16 + (l&15)]
// w2p[i], i = ((nt*2+kk)*64 + l)*8 + j  -> W2[kk*32 + 8*(l>>4) + j][nt*16 + (l&15)]
__global__ void k_prep(const float* __restrict__ W1, const float* __restrict__ W2,
                       unsigned short* __restrict__ w1p, unsigned short* __restrict__ w2p) {
    const int t = threadIdx.x;
#pragma unroll
    for (int k = 0; k < 32; ++k) {
        int i = t + 256 * k;                       // 8192
        int j = i & 7, l = (i >> 3) & 63, kk = (i >> 9) & 3, nt = i >> 11;
        int c = kk * 32 + 8 * (l >> 4) + j, n = nt * 16 + (l & 15);
        w1p[i] = f2bf(W1[c * ND + n]);
    }
#pragma unroll
    for (int k = 0; k < 16; ++k) {
        int i = t + 256 * k;                       // 4096
        int j = i & 7, l = (i >> 3) & 63, kk = (i >> 9) & 1, nt = (i >> 10) & 3;
        int c = kk * 32 + 8 * (l >> 4) + j, n = nt * 16 + (l & 15);
        w2p[i] = f2bf(W2[c * ND + n]);
    }
}

// ---------- k_mlp1: U[px][n] = (fm @ W1), dense, straight from NCHW fp32 ----------
// 1024 blocks x 256 thr; 128 pixels/block, 32/wave. XCD-swizzled so batch 4x..4x+3
// lands on XCD x (matches k_fused2's mapping -> U stays in that XCD's L2).
__global__ __launch_bounds__(256) void k_mlp1(const float* __restrict__ fm,
                                              const unsigned short* __restrict__ w1p,
                                              unsigned short* __restrict__ U) {
    __shared__ __align__(16) unsigned short w1s[8192];   // 16 KB, fragment order
    const int t = threadIdx.x;
#pragma unroll
    for (int k = 0; k < 4; ++k) {
        int i = t + 256 * k;                       // 1024 chunks of 16 B, linear
        *(u16x8*)&w1s[i * 8] = *(const u16x8*)&w1p[i * 8];
    }
    __syncthreads();

    const int bid = blockIdx.x;
    const int swz = (bid & 7) * 128 + (bid >> 3);  // bijective on 1024
    const int lane = t & 63, wv = t >> 6;
    const int g = lane >> 4, mr = lane & 15;
    const int p0  = swz * 128 + wv * 32;           // wave's first global pixel
    const int b   = p0 >> 12;                      // batch (block stays in one batch)
    const int pin = p0 & 4095;
    const float* fb = fm + (size_t)b * (Cc * HW);

    // A-fragments: lane (g,mr) rows {pin+mr, pin+16+mr}, channels kk*32+8g+j
    bf16x8 aF[2][4];
#pragma unroll
    for (int half = 0; half < 2; ++half) {
        const int px = pin + half * 16 + mr;
#pragma unroll
        for (int kk = 0; kk < 4; ++kk) {
            float v[8];
#pragma unroll
            for (int j = 0; j < 8; ++j)
                v[j] = fb[(size_t)(kk * 32 + 8 * g + j) * HW + px];
            u16x8 o;
#pragma unroll
            for (int j = 0; j < 8; ++j) o[j] = f2bf(v[j]);
            aF[half][kk] = __builtin_bit_cast(bf16x8, o);
        }
    }

    f32x4 acc[2][4];
#pragma unroll
    for (int mt = 0; mt < 2; ++mt)
#pragma unroll
        for (int nt = 0; nt < 4; ++nt) acc[mt][nt] = (f32x4){0.f, 0.f, 0.f, 0.f};

#pragma unroll
    for (int kk = 0; kk < 4; ++kk)
#pragma unroll
        for (int nt = 0; nt < 4; ++nt) {
            bf16x8 bF = *(const bf16x8*)&w1s[((nt * 4 + kk) * 64 + lane) * 8];
            acc[0][nt] = __builtin_amdgcn_mfma_f32_16x16x32_bf16(aF[0][kk], bF, acc[0][nt], 0, 0, 0);
            acc[1][nt] = __builtin_amdgcn_mfma_f32_16x16x32_bf16(aF[1][kk], bF, acc[1][nt], 0, 0, 0);
        }

    // store U (natural channel order): row = p0 + mt*16 + 4g + r, col = nt*16 + mr
#pragma unroll
    for (int mt = 0; mt < 2; ++mt)
#pragma unroll
        for (int nt = 0; nt < 4; ++nt)
#pragma unroll
            for (int r = 0; r < 4; ++r) {
                const int row = p0 + mt * 16 + 4 * g + r;
                U[(size_t)row * ND + nt * 16 + mr] = f2bf(acc[mt][nt][r]);
            }
}

// ---------- k_fused2: gather U + interp + b1/relu -> GEMM2 -> normalize ----------
// 2048 blocks x 256 thr; 64 samples/block, 16/wave. Interp lands directly in
// GEMM2 A-fragment layout (lane (g,mr): sample m0+mr, channels kk*32+8g+j).
__global__ __launch_bounds__(256) void k_fused2(const unsigned short* __restrict__ U,
                                                const float* __restrict__ pc,
                                                const unsigned short* __restrict__ w2p,
                                                const float* __restrict__ b1,
                                                const float* __restrict__ b2,
                                                float* __restrict__ out) {
    __shared__ __align__(16) unsigned short w2s[4096];   // 8 KB, fragment order
    __shared__ __align__(16) float b1s[64];
    __shared__ __align__(16) float b2s[64];
    const int t = threadIdx.x;
#pragma unroll
    for (int k = 0; k < 2; ++k) {
        int i = t + 256 * k;
        *(u16x8*)&w2s[i * 8] = *(const u16x8*)&w2p[i * 8];
    }
    if (t < 64) { b1s[t] = b1[t]; b2s[t] = b2[t]; }
    __syncthreads();

    const int bid = blockIdx.x;
    const int swz = (bid & 7) * 256 + (bid >> 3);  // bijective on 2048
    const int lane = t & 63, wv = t >> 6;
    const int g = lane >> 4, mr = lane & 15;
    const int m0 = swz * 64 + wv * 16;
    const int sm = m0 + mr;                        // this lane's A-side sample

    const float y = pc[2 * (size_t)sm + 0];
    const float x = pc[2 * (size_t)sm + 1];
    const float yf = floorf(y), xf = floorf(x);
    const float ty = y - yf, tx = x - xf;
    int y0 = min(max((int)yf, 0), Hh - 1);
    int x0 = min(max((int)xf, 0), Ww - 1);
    int y1 = min(y0 + 1, Hh - 1);
    int x1 = min(x0 + 1, Ww - 1);
    const float w00 = (1.f - ty) * (1.f - tx), w01 = (1.f - ty) * tx;
    const float w10 = ty * (1.f - tx),         w11 = ty * tx;
    const int bb = sm >> 12;                       // batch (block stays in one batch)
    const unsigned short* Ub = U + (size_t)bb * (HW * ND) + 8 * g;
    const u16x8* q00 = (const u16x8*)(Ub + (y0 * Ww + x0) * ND);
    const u16x8* q01 = (const u16x8*)(Ub + (y0 * Ww + x1) * ND);
    const u16x8* q10 = (const u16x8*)(Ub + (y1 * Ww + x0) * ND);
    const u16x8* q11 = (const u16x8*)(Ub + (y1 * Ww + x1) * ND);

    bf16x8 aF[2];
#pragma unroll
    for (int kk = 0; kk < 2; ++kk) {
        u16x8 a = q00[kk * 4], c0 = q01[kk * 4], c1 = q10[kk * 4], d = q11[kk * 4];
        f32x4 bA = *(const f32x4*)&b1s[kk * 32 + 8 * g];
        f32x4 bB = *(const f32x4*)&b1s[kk * 32 + 8 * g + 4];
        u16x8 o;
#pragma unroll
        for (int j = 0; j < 8; ++j) {
            float v = w00 * bf2f(a[j]) + w01 * bf2f(c0[j])
                    + w10 * bf2f(c1[j]) + w11 * bf2f(d[j]);
            float bv = (j < 4) ? bA[j & 3] : bB[j & 3];
            o[j] = f2bf(fmaxf(v + bv, 0.f));
        }
        aF[kk] = __builtin_bit_cast(bf16x8, o);
    }

    f32x4 acc2[4];
#pragma unroll
    for (int nt = 0; nt < 4; ++nt) {
        const float bc = b2s[nt * 16 + mr];
        acc2[nt] = (f32x4){bc, bc, bc, bc};
    }
#pragma unroll
    for (int kk = 0; kk < 2; ++kk)
#pragma unroll
        for (int nt = 0; nt < 4; ++nt) {
            bf16x8 bF = *(const bf16x8*)&w2s[((nt * 2 + kk) * 64 + lane) * 8];
            acc2[nt] = __builtin_amdgcn_mfma_f32_16x16x32_bf16(aF[kk], bF, acc2[nt], 0, 0, 0);
        }

    // normalize rows (this lane holds rows m0+4g+r, cols nt*16+mr) + store
    f32x4 ss = (f32x4){0.f, 0.f, 0.f, 0.f};
#pragma unroll
    for (int nt = 0; nt < 4; ++nt)
#pragma unroll
        for (int r = 0; r < 4; ++r) ss[r] += acc2[nt][r] * acc2[nt][r];
#pragma unroll
    for (int off = 1; off <= 8; off <<= 1) {
#pragma unroll
        for (int r = 0; r < 4; ++r) ss[r] += __shfl_xor(ss[r], off);
    }
#pragma unroll
    for (int r = 0; r < 4; ++r) {
        const float inv = 1.f / fmaxf(sqrtf(ss[r]), 1e-12f);
        const size_t ob = (size_t)(m0 + 4 * g + r) * ND;
#pragma unroll
        for (int nt = 0; nt < 4; ++nt)
            out[ob + nt * 16 + mr] = acc2[nt][r] * inv;
    }
}

extern "C" void kernel_launch(void* const* d_in, const int* in_sizes, int n_in,
                              void* d_out, int out_size, void* d_ws, size_t ws_size,
                              hipStream_t stream) {
    const float* fm = (const float*)d_in[0];
    const float* pc = (const float*)d_in[1];
    const float* W1 = (const float*)d_in[2];
    const float* b1 = (const float*)d_in[3];
    const float* W2 = (const float*)d_in[4];
    const float* b2 = (const float*)d_in[5];
    float* out = (float*)d_out;

    unsigned short* U   = (unsigned short*)d_ws;          // 131072 x 64 bf16 = 16 MB
    unsigned short* w1p = U + (size_t)NPX * ND;           // 8192 u16
    unsigned short* w2p = w1p + 8192;                     // 4096 u16

    k_prep<<<1, 256, 0, stream>>>(W1, W2, w1p, w2p);
    k_mlp1<<<NPX / 128, 256, 0, stream>>>(fm, w1p, U);
    k_fused2<<<(BSz * TOPK) / 64, 256, 0, stream>>>(U, pc, w2p, b1, b2, out);
}